// Round 1
// baseline (47.751 us; speedup 1.0000x reference)
//
#include <hip/hip_runtime.h>

#define HH 64
#define WW 64
#define NPIX 4096
#define NT 100
#define PPT 16  // pixels per thread (4096 / 256)

// Lock-free union-find in LDS. Convention: parent index strictly decreases
// along chains (min-root), so all loops terminate and no cycles form.
__device__ __forceinline__ int find_root(int* P, int x) {
    // path-halving find
    int p = P[x];
    while (p != x) {
        int gp = P[p];
        P[x] = gp;      // benign racy write: gp is an ancestor, gp < x
        x = gp;
        p = P[x];
    }
    return x;
}

__device__ __forceinline__ void unite(int* P, int a, int b) {
    a = find_root(P, a);
    b = find_root(P, b);
    while (a != b) {
        if (a < b) { int t = a; a = b; b = t; }   // a > b: hook a under b
        int old = atomicCAS(&P[a], a, b);
        if (old == a) return;
        a = find_root(P, old);
        b = find_root(P, b);
    }
}

__device__ __forceinline__ int wave_sum(int v) {
    #pragma unroll
    for (int o = 32; o > 0; o >>= 1) v += __shfl_down(v, o, 64);
    return v;
}

__global__ __launch_bounds__(256)
void betti_err_kernel(const float* __restrict__ prob,   // [8,3,64,64]
                      const int*  __restrict__ gt,      // [8,3,100,2]
                      float* __restrict__ out)          // [8]
{
    __shared__ int P[NPIX];
    __shared__ int wsum[4][4];   // [wave][quantity]

    const int bid = blockIdx.x;          // (b*2 + c)*100 + t
    const int t   = bid % NT;
    const int cb  = bid / NT;
    const int c   = cb & 1;
    const int b   = cb >> 1;

    const float thr = (float)t * (1.0f / 99.0f);
    const float* img = prob + (size_t)(b * 3 + c) * NPIX;

    const int tid = threadIdx.x;

    // ---- binarize + init union-find ----
    int px = 0;
    #pragma unroll
    for (int k = 0; k < PPT; ++k) {
        int i = tid + k * 256;           // coalesced global, conflict-free LDS
        bool m = img[i] > thr;
        P[i] = m ? i : -1;
        px += m ? 1 : 0;
    }
    __syncthreads();

    // ---- union pass (right + down edges), count edges ----
    int eh = 0, ev = 0;
    #pragma unroll
    for (int k = 0; k < PPT; ++k) {
        int i = tid + k * 256;
        if (P[i] < 0) continue;
        int x = i & 63;
        if (x < 63 && P[i + 1] >= 0)  { eh++; unite(P, i, i + 1); }
        if (i < NPIX - WW && P[i + WW] >= 0) { ev++; unite(P, i, i + WW); }
    }
    __syncthreads();

    // ---- count roots = component count ----
    int roots = 0;
    #pragma unroll
    for (int k = 0; k < PPT; ++k) {
        int i = tid + k * 256;
        roots += (P[i] == i) ? 1 : 0;
    }

    // ---- block reduction of {px, eh, ev, roots} ----
    const int wave = tid >> 6;
    const int lane = tid & 63;
    int q0 = wave_sum(px);
    int q1 = wave_sum(eh);
    int q2 = wave_sum(ev);
    int q3 = wave_sum(roots);
    if (lane == 0) {
        wsum[wave][0] = q0; wsum[wave][1] = q1;
        wsum[wave][2] = q2; wsum[wave][3] = q3;
    }
    __syncthreads();

    if (tid == 0) {
        int spx = 0, seh = 0, sev = 0, sroots = 0;
        #pragma unroll
        for (int w = 0; w < 4; ++w) {
            spx += wsum[w][0]; seh += wsum[w][1];
            sev += wsum[w][2]; sroots += wsum[w][3];
        }
        int b0 = sroots;
        int euler = spx - (seh + sev);
        int b1 = b0 - euler;

        long long contrib = 0;
        if (c == 0) {
            // inside betti vs gt[:,0] AND (union := inside) vs gt[:,2]
            const int* g0 = gt + (((size_t)b * 3 + 0) * NT + t) * 2;
            const int* g2 = gt + (((size_t)b * 3 + 2) * NT + t) * 2;
            int d;
            d = b0 - g0[0]; contrib += d < 0 ? -d : d;
            d = b1 - g0[1]; contrib += d < 0 ? -d : d;
            d = b0 - g2[0]; contrib += d < 0 ? -d : d;
            d = b1 - g2[1]; contrib += d < 0 ? -d : d;
        } else {
            const int* g1 = gt + (((size_t)b * 3 + 1) * NT + t) * 2;
            int d;
            d = b0 - g1[0]; contrib += d < 0 ? -d : d;
            d = b1 - g1[1]; contrib += d < 0 ? -d : d;
        }
        // integer-valued float adds < 2^24: exact & order-independent
        atomicAdd(&out[b], (float)contrib);
    }
}

extern "C" void kernel_launch(void* const* d_in, const int* in_sizes, int n_in,
                              void* d_out, int out_size, void* d_ws, size_t ws_size,
                              hipStream_t stream) {
    const float* prob = (const float*)d_in[0];   // [8,3,64,64] f32
    const int*   gt   = (const int*)d_in[1];     // [8,3,100,2] i32
    float* out = (float*)d_out;                  // [8] f32

    hipMemsetAsync(out, 0, (size_t)out_size * sizeof(float), stream);

    const int B = 8;
    const int nblocks = B * 2 * NT;   // 1600
    betti_err_kernel<<<nblocks, 256, 0, stream>>>(prob, gt, out);
}

// Round 2
// 33.284 us; speedup vs baseline: 1.4347x; 1.4347x over previous
//
#include <hip/hip_runtime.h>

#define NT 100

// Lock-free min-root union-find in LDS over run ids. Parent strictly
// decreases along chains -> termination, no cycles.
__device__ __forceinline__ int find_root(int* P, int x) {
    int p = P[x];
    while (p != x) {
        int gp = P[p];
        P[x] = gp;          // benign racy path-halving (gp is an ancestor, gp < x)
        x = gp;
        p = P[x];
    }
    return x;
}

__device__ __forceinline__ void unite(int* P, int a, int b) {
    a = find_root(P, a);
    b = find_root(P, b);
    while (a != b) {
        if (a < b) { int t = a; a = b; b = t; }   // hook larger under smaller
        int old = atomicCAS(&P[a], a, b);
        if (old == a) return;
        a = find_root(P, old);
        b = find_root(P, b);
    }
}

__device__ __forceinline__ int wave_sum(int v) {
    #pragma unroll
    for (int o = 32; o > 0; o >>= 1) v += __shfl_down(v, o, 64);
    return v;
}

// One 64-lane wave per (b, c, t). Lane r owns row r as a 64-bit mask.
__global__ __launch_bounds__(64)
void betti_err_kernel(const float* __restrict__ prob,   // [8,3,64,64]
                      const int*  __restrict__ gt,      // [8,3,100,2]
                      float* __restrict__ out)          // [8]
{
    __shared__ int P[2048];          // run id = k*64 + row, k < 32

    const int bid = blockIdx.x;      // (b*2 + c)*100 + t
    const int t   = bid % NT;
    const int cb  = bid / NT;
    const int c   = cb & 1;
    const int b   = cb >> 1;

    const float thr = (float)t * (1.0f / 99.0f);
    const float* img = prob + (size_t)(b * 3 + c) * 4096;
    const int lane = threadIdx.x;

    // ---- build row masks via ballot: lane r keeps row r ----
    unsigned long long mrow = 0;
    #pragma unroll 16
    for (int r = 0; r < 64; ++r) {
        float v = img[r * 64 + lane];                 // coalesced, L1/L2-hot
        unsigned long long bal = __ballot(v > thr);
        if (lane == r) mrow = bal;
    }

    // neighbor-row data via shuffle
    unsigned long long up = __shfl_up(mrow, 1, 64);
    unsigned long long starts = mrow & ~(mrow << 1);  // run starts in this row
    unsigned long long starts_up = __shfl_up(starts, 1, 64);
    if (lane == 0) { up = 0ull; starts_up = 0ull; }

    const int px = __popcll(mrow);
    const int eh = __popcll(mrow & (mrow >> 1));      // horizontal 4-edges
    const int ev = __popcll(mrow & up);               // vertical 4-edges
    const int nruns = __popcll(starts);

    // ---- init union-find (conflict-free: bank = lane%32, 2-way = free) ----
    #pragma unroll
    for (int k = 0; k < 32; ++k)
        P[k * 64 + lane] = k * 64 + lane;
    __syncthreads();

    // ---- one union per vertical overlap segment ----
    unsigned long long ov = mrow & up;
    unsigned long long ss = ov & ~(ov << 1);          // segment starts
    while (ss) {
        int j = __ffsll((long long)ss) - 1;
        ss &= ss - 1;
        unsigned long long le = (2ull << j) - 1;      // bits [0..j]; j=63 -> all ones
        int kc = __popcll(starts    & le) - 1;        // my run index at col j
        int ku = __popcll(starts_up & le) - 1;        // upper run index at col j
        unite(P, kc * 64 + lane, ku * 64 + (lane - 1));
    }
    __syncthreads();

    // ---- count roots among real runs ----
    int roots = 0;
    for (int k = 0; k < nruns; ++k)
        roots += (P[k * 64 + lane] == k * 64 + lane) ? 1 : 0;

    // ---- wave reduction + output ----
    int q_px = wave_sum(px);
    int q_eh = wave_sum(eh);
    int q_ev = wave_sum(ev);
    int q_b0 = wave_sum(roots);

    if (lane == 0) {
        int b0 = q_b0;
        int euler = q_px - (q_eh + q_ev);
        int b1 = b0 - euler;

        int contrib = 0, d;
        if (c == 0) {
            const int* g0 = gt + (((size_t)b * 3 + 0) * NT + t) * 2;
            const int* g2 = gt + (((size_t)b * 3 + 2) * NT + t) * 2;
            d = b0 - g0[0]; contrib += d < 0 ? -d : d;
            d = b1 - g0[1]; contrib += d < 0 ? -d : d;
            d = b0 - g2[0]; contrib += d < 0 ? -d : d;
            d = b1 - g2[1]; contrib += d < 0 ? -d : d;
        } else {
            const int* g1 = gt + (((size_t)b * 3 + 1) * NT + t) * 2;
            d = b0 - g1[0]; contrib += d < 0 ? -d : d;
            d = b1 - g1[1]; contrib += d < 0 ? -d : d;
        }
        // integer-valued float adds < 2^24: exact & order-independent
        atomicAdd(&out[b], (float)contrib);
    }
}

extern "C" void kernel_launch(void* const* d_in, const int* in_sizes, int n_in,
                              void* d_out, int out_size, void* d_ws, size_t ws_size,
                              hipStream_t stream) {
    const float* prob = (const float*)d_in[0];   // [8,3,64,64] f32
    const int*   gt   = (const int*)d_in[1];     // [8,3,100,2] i32
    float* out = (float*)d_out;                  // [8] f32

    hipMemsetAsync(out, 0, (size_t)out_size * sizeof(float), stream);

    const int nblocks = 8 * 2 * NT;   // 1600 waves, one per (b,c,t)
    betti_err_kernel<<<nblocks, 64, 0, stream>>>(prob, gt, out);
}

// Round 3
// 29.053 us; speedup vs baseline: 1.6436x; 1.1456x over previous
//
#include <hip/hip_runtime.h>

#define NT 100

// Lock-free min-root union-find in LDS over run ids. Parent strictly
// decreases along chains -> termination, no cycles.
__device__ __forceinline__ int find_root(int* P, int x) {
    int p = P[x];
    while (p != x) {
        int gp = P[p];
        P[x] = gp;          // benign racy path-halving (gp is an ancestor, gp < x)
        x = gp;
        p = P[x];
    }
    return x;
}

__device__ __forceinline__ void unite(int* P, int a, int b) {
    a = find_root(P, a);
    b = find_root(P, b);
    while (a != b) {
        if (a < b) { int t = a; a = b; b = t; }   // hook larger under smaller
        int old = atomicCAS(&P[a], a, b);
        if (old == a) return;
        a = find_root(P, old);
        b = find_root(P, b);
    }
}

// One 64-lane wave per (b, c, t). Lane r owns row r as a 64-bit mask.
__global__ __launch_bounds__(64)
void betti_partial(const float* __restrict__ prob,   // [8,3,64,64]
                   const int*  __restrict__ gt,      // [8,3,100,2]
                   int* __restrict__ part)           // [1600] = [8][2][100]
{
    __shared__ int P[2048];          // run id = k*64 + row, k < 32

    const int bid = blockIdx.x;      // (b*2 + c)*100 + t
    const int t   = bid % NT;
    const int cb  = bid / NT;
    const int c   = cb & 1;
    const int b   = cb >> 1;

    const float thr = (float)t * (1.0f / 99.0f);
    const float* img = prob + (size_t)(b * 3 + c) * 4096;
    const int lane = threadIdx.x;

    // ---- lane r loads its own row (16 x float4), builds 64-bit mask ----
    const float4* rp = (const float4*)(img + (lane << 6));
    unsigned long long mrow = 0ull;
    #pragma unroll
    for (int k = 0; k < 16; ++k) {
        float4 v = rp[k];
        mrow |= (unsigned long long)(v.x > thr) << (4 * k + 0);
        mrow |= (unsigned long long)(v.y > thr) << (4 * k + 1);
        mrow |= (unsigned long long)(v.z > thr) << (4 * k + 2);
        mrow |= (unsigned long long)(v.w > thr) << (4 * k + 3);
    }

    // ---- init union-find (bank = lane%32, 2-way = free) ----
    #pragma unroll
    for (int k = 0; k < 32; ++k)
        P[(k << 6) + lane] = (k << 6) + lane;

    // neighbor-row data via shuffle
    unsigned long long up = __shfl_up(mrow, 1, 64);
    unsigned long long starts = mrow & ~(mrow << 1);  // run starts in this row
    unsigned long long starts_up = __shfl_up(starts, 1, 64);
    if (lane == 0) { up = 0ull; starts_up = 0ull; }

    const int px = __popcll(mrow);
    const int eh = __popcll(mrow & (mrow >> 1));      // horizontal 4-edges
    const int ev = __popcll(mrow & up);               // vertical 4-edges
    const int nruns = __popcll(starts);

    __syncthreads();

    // ---- one union per vertical overlap segment ----
    unsigned long long ov = mrow & up;
    unsigned long long ss = ov & ~(ov << 1);          // segment starts
    while (ss) {
        int j = __ffsll((long long)ss) - 1;
        ss &= ss - 1;
        unsigned long long le = (2ull << j) - 1;      // bits [0..j]
        int kc = __popcll(starts    & le) - 1;        // my run index at col j
        int ku = __popcll(starts_up & le) - 1;        // upper run index at col j
        unite(P, (kc << 6) + lane, (ku << 6) + (lane - 1));
    }
    __syncthreads();

    // ---- branch-free root count: scan all 32 slots, subtract phantoms ----
    // slots k >= nruns were never united -> always self-rooted
    int selfc = 0;
    #pragma unroll
    for (int k = 0; k < 32; ++k) {
        int s = (k << 6) + lane;
        selfc += (P[s] == s) ? 1 : 0;
    }
    const int roots = selfc - (32 - nruns);

    // ---- single packed 64-bit wave reduction: px|eh|ev|roots (16b each) ----
    unsigned long long pk = (unsigned long long)px
                          | ((unsigned long long)eh    << 16)
                          | ((unsigned long long)ev    << 32)
                          | ((unsigned long long)roots << 48);
    #pragma unroll
    for (int o = 32; o > 0; o >>= 1)
        pk += __shfl_down(pk, o, 64);

    if (lane == 0) {
        const int spx = (int)(pk        & 0xffff);
        const int seh = (int)((pk >> 16) & 0xffff);
        const int sev = (int)((pk >> 32) & 0xffff);
        const int b0  = (int)((pk >> 48) & 0xffff);
        const int euler = spx - (seh + sev);
        const int b1 = b0 - euler;

        int contrib = 0, d;
        if (c == 0) {
            const int* g0 = gt + (((size_t)b * 3 + 0) * NT + t) * 2;
            const int* g2 = gt + (((size_t)b * 3 + 2) * NT + t) * 2;
            d = b0 - g0[0]; contrib += d < 0 ? -d : d;
            d = b1 - g0[1]; contrib += d < 0 ? -d : d;
            d = b0 - g2[0]; contrib += d < 0 ? -d : d;
            d = b1 - g2[1]; contrib += d < 0 ? -d : d;
        } else {
            const int* g1 = gt + (((size_t)b * 3 + 1) * NT + t) * 2;
            d = b0 - g1[0]; contrib += d < 0 ? -d : d;
            d = b1 - g1[1]; contrib += d < 0 ? -d : d;
        }
        part[bid] = contrib;           // plain store, no init needed
    }
}

// 8 blocks: block b sums part[b*200 .. b*200+200) and plain-stores out[b].
__global__ __launch_bounds__(256)
void betti_reduce(const int* __restrict__ part, float* __restrict__ out) {
    __shared__ int wsum[4];
    const int b = blockIdx.x;
    const int tid = threadIdx.x;
    int v = (tid < 200) ? part[b * 200 + tid] : 0;
    #pragma unroll
    for (int o = 32; o > 0; o >>= 1) v += __shfl_down(v, o, 64);
    if ((tid & 63) == 0) wsum[tid >> 6] = v;
    __syncthreads();
    if (tid == 0)
        out[b] = (float)(wsum[0] + wsum[1] + wsum[2] + wsum[3]);
}

extern "C" void kernel_launch(void* const* d_in, const int* in_sizes, int n_in,
                              void* d_out, int out_size, void* d_ws, size_t ws_size,
                              hipStream_t stream) {
    const float* prob = (const float*)d_in[0];   // [8,3,64,64] f32
    const int*   gt   = (const int*)d_in[1];     // [8,3,100,2] i32
    float* out = (float*)d_out;                  // [8] f32
    int* part = (int*)d_ws;                      // 1600 ints scratch

    const int nblocks = 8 * 2 * NT;   // 1600 waves, one per (b,c,t)
    betti_partial<<<nblocks, 64, 0, stream>>>(prob, gt, part);
    betti_reduce<<<8, 256, 0, stream>>>(part, out);
}

// Round 6
// 19.391 us; speedup vs baseline: 2.4626x; 1.4983x over previous
//
#include <hip/hip_runtime.h>

#define NT 100

// Lock-free min-root union-find in LDS. Parent strictly decreases along
// chains -> termination, no cycles.
__device__ __forceinline__ int find_root(int* P, int x) {
    int p = P[x];
    while (p != x) {
        int gp = P[p];
        P[x] = gp;          // benign racy path-halving (gp is an ancestor, gp < x)
        x = gp;
        p = P[x];
    }
    return x;
}

__device__ __forceinline__ void unite(int* P, int a, int b) {
    a = find_root(P, a);
    b = find_root(P, b);
    while (a != b) {
        if (a < b) { int t = a; a = b; b = t; }   // hook larger under smaller
        int old = atomicCAS(&P[a], a, b);
        if (old == a) return;
        a = find_root(P, old);
        b = find_root(P, b);
    }
}

// One 256-thread block per (b, c, t). Wave h owns column quarter
// [16h, 16h+16); lane r of wave h owns row r of that quarter (16-bit mask).
// Run id = ((h*8 + k) << 6) | row,  k < 8 (max 8 runs per 16 cols).
__global__ __launch_bounds__(256)
void betti_partial(const float* __restrict__ prob,   // [8,3,64,64]
                   const int*  __restrict__ gt,      // [8,3,100,2]
                   int* __restrict__ part)           // [1600]
{
    __shared__ int P[2048];
    __shared__ int bL[3][64];                 // run id at col 16h+15, or -1
    __shared__ int bR[3][64];                 // run id at col 16(h+1), or -1
    __shared__ unsigned long long wred[4];

    const int bid = blockIdx.x;               // (b*2 + c)*100 + t
    const int t   = bid % NT;
    const int cb  = bid / NT;
    const int c   = cb & 1;
    const int b   = cb >> 1;

    const float thr = (float)t * (1.0f / 99.0f);
    const float* img = prob + (size_t)(b * 3 + c) * 4096;

    const int tid  = threadIdx.x;
    const int h    = tid >> 6;                // wave = column quarter
    const int lane = tid & 63;                // row

    // ---- load row `lane`, cols 16h..16h+15 (4 x float4), build 16-bit mask ----
    const float4* rp = (const float4*)(img + (lane << 6) + (h << 4));
    unsigned int m = 0;
    #pragma unroll
    for (int q = 0; q < 4; ++q) {
        float4 v = rp[q];
        m |= (unsigned)(v.x > thr) << (4 * q + 0);
        m |= (unsigned)(v.y > thr) << (4 * q + 1);
        m |= (unsigned)(v.z > thr) << (4 * q + 2);
        m |= (unsigned)(v.w > thr) << (4 * q + 3);
    }

    // ---- init my 8 UF slots ----
    #pragma unroll
    for (int k = 0; k < 8; ++k) {
        int s = ((h * 8 + k) << 6) | lane;
        P[s] = s;
    }

    const unsigned um = m & 0xFFFFu;
    unsigned up        = (unsigned)__shfl_up((int)um, 1, 64);
    unsigned starts    = um & ~(um << 1) & 0xFFFFu;       // run starts
    unsigned starts_up = (unsigned)__shfl_up((int)starts, 1, 64);
    if (lane == 0) { up = 0u; starts_up = 0u; }

    const int px    = __popc(um);
    const int eh    = __popc(um & (um >> 1));             // horiz edges in quarter
    const int ev    = __popc(um & up);                    // vert edges in quarter
    const int nruns = __popc(starts);

    // ---- boundary descriptors (written pre-barrier, read post-barrier) ----
    if (h < 3)   // run containing col15 is the last-starting run: index nruns-1
        bL[h][lane] = ((um >> 15) & 1u) ? (((h * 8 + (nruns - 1)) << 6) | lane) : -1;
    if (h > 0)   // if col 16h is set, it is a run start: index 0
        bR[h - 1][lane] = (um & 1u) ? (((h * 8) << 6) | lane) : -1;

    __syncthreads();

    // ---- vertical-overlap segment unions within quarter ----
    unsigned ov = um & up;
    unsigned ss = ov & ~(ov << 1) & 0xFFFFu;              // segment starts
    while (ss) {
        int j = __ffs(ss) - 1;
        ss &= ss - 1;
        unsigned le = (2u << j) - 1;                      // bits [0..j]
        int kc = __popc(starts    & le) - 1;
        int ku = __popc(starts_up & le) - 1;
        unite(P, ((h * 8 + kc) << 6) | lane, ((h * 8 + ku) << 6) | (lane - 1));
    }

    // ---- boundary unions + crossing horizontal edges (waves 0..2) ----
    int ehx = 0;
    if (h < 3) {
        int l = bL[h][lane], r = bR[h][lane];
        if (l >= 0 && r >= 0) { ehx = 1; unite(P, l, r); }
    }
    __syncthreads();

    // ---- roots among my 8 slots, minus phantoms (untouched => self-rooted) ----
    int selfc = 0;
    #pragma unroll
    for (int k = 0; k < 8; ++k) {
        int s = ((h * 8 + k) << 6) | lane;
        selfc += (P[s] == s) ? 1 : 0;
    }
    const int roots = selfc - (8 - nruns);

    // ---- packed {px, eh+ehx, ev, roots} wave reduce, then block combine ----
    unsigned long long pk = (unsigned long long)px
                          | ((unsigned long long)(eh + ehx) << 16)
                          | ((unsigned long long)ev         << 32)
                          | ((unsigned long long)roots      << 48);
    #pragma unroll
    for (int o = 32; o > 0; o >>= 1)
        pk += __shfl_down(pk, o, 64);
    if (lane == 0) wred[h] = pk;
    __syncthreads();

    if (tid == 0) {
        unsigned long long s = wred[0] + wred[1] + wred[2] + wred[3];
        const int spx = (int)(s         & 0xffff);
        const int seh = (int)((s >> 16) & 0xffff);
        const int sev = (int)((s >> 32) & 0xffff);
        const int b0  = (int)((s >> 48) & 0xffff);
        const int euler = spx - (seh + sev);
        const int b1 = b0 - euler;

        int contrib = 0, d;
        if (c == 0) {
            const int* g0 = gt + (((size_t)b * 3 + 0) * NT + t) * 2;
            const int* g2 = gt + (((size_t)b * 3 + 2) * NT + t) * 2;
            d = b0 - g0[0]; contrib += d < 0 ? -d : d;
            d = b1 - g0[1]; contrib += d < 0 ? -d : d;
            d = b0 - g2[0]; contrib += d < 0 ? -d : d;
            d = b1 - g2[1]; contrib += d < 0 ? -d : d;
        } else {
            const int* g1 = gt + (((size_t)b * 3 + 1) * NT + t) * 2;
            d = b0 - g1[0]; contrib += d < 0 ? -d : d;
            d = b1 - g1[1]; contrib += d < 0 ? -d : d;
        }
        part[bid] = contrib;                  // plain store, no init needed
    }
}

// 8 blocks: block b sums part[b*200 .. b*200+200) and plain-stores out[b].
__global__ __launch_bounds__(256)
void betti_reduce(const int* __restrict__ part, float* __restrict__ out) {
    __shared__ int wsum[4];
    const int b = blockIdx.x;
    const int tid = threadIdx.x;
    int v = (tid < 200) ? part[b * 200 + tid] : 0;
    #pragma unroll
    for (int o = 32; o > 0; o >>= 1) v += __shfl_down(v, o, 64);
    if ((tid & 63) == 0) wsum[tid >> 6] = v;
    __syncthreads();
    if (tid == 0)
        out[b] = (float)(wsum[0] + wsum[1] + wsum[2] + wsum[3]);
}

extern "C" void kernel_launch(void* const* d_in, const int* in_sizes, int n_in,
                              void* d_out, int out_size, void* d_ws, size_t ws_size,
                              hipStream_t stream) {
    const float* prob = (const float*)d_in[0];   // [8,3,64,64] f32
    const int*   gt   = (const int*)d_in[1];     // [8,3,100,2] i32
    float* out = (float*)d_out;                  // [8] f32
    int* part = (int*)d_ws;                      // 1600 ints scratch

    const int nblocks = 8 * 2 * NT;   // 1600 blocks, one per (b,c,t)
    betti_partial<<<nblocks, 256, 0, stream>>>(prob, gt, part);
    betti_reduce<<<8, 256, 0, stream>>>(part, out);
}

// Round 7
// 19.297 us; speedup vs baseline: 2.4745x; 1.0049x over previous
//
#include <hip/hip_runtime.h>

typedef unsigned long long ull;
#define NT 100

// Lock-free min-root union-find in LDS. Parent strictly decreases along
// chains -> termination, no cycles.
__device__ __forceinline__ int find_root(int* P, int x) {
    int p = P[x];
    while (p != x) {
        int gp = P[p];
        P[x] = gp;          // benign racy path-halving (gp is an ancestor, gp < x)
        x = gp;
        p = P[x];
    }
    return x;
}

// Returns 1 iff this call performed the hook (merged two distinct trees).
// Total successful hooks per block == components merged (schedule-invariant).
__device__ __forceinline__ int unite(int* P, int a, int b) {
    a = find_root(P, a);
    b = find_root(P, b);
    while (a != b) {
        if (a < b) { int t = a; a = b; b = t; }   // hook larger under smaller
        int old = atomicCAS(&P[a], a, b);
        if (old == a) return 1;
        a = find_root(P, old);
        b = find_root(P, b);
    }
    return 0;
}

// One 256-thread block per (b, c, t). Wave h owns column quarter
// [16h, 16h+16); lane r of wave h owns row r of that quarter (16-bit mask).
// Run id = ((h*8 + k) << 6) | row,  k < 8 (max 8 runs per 16 cols).
// Per-wave packed partial {px|eh|ev|nruns|merges} -> ws[bid*4 + h].
__global__ __launch_bounds__(256)
void betti_partial(const float* __restrict__ prob,   // [8,3,64,64]
                   ull* __restrict__ ws)             // [1600*4]
{
    __shared__ int P[2048];
    __shared__ int bL[3][64];                 // run id at col 16h+15, or -1
    __shared__ int bR[3][64];                 // run id at col 16(h+1), or -1

    const int bid = blockIdx.x;               // (b*2 + c)*100 + t
    const int t   = bid % NT;
    const int cb  = bid / NT;

    const float thr = (float)t * (1.0f / 99.0f);
    const float* img = prob + (size_t)((cb >> 1) * 3 + (cb & 1)) * 4096;

    const int tid  = threadIdx.x;
    const int h    = tid >> 6;                // wave = column quarter
    const int lane = tid & 63;                // row

    // ---- load row `lane`, cols 16h..16h+15 (4 x float4), build 16-bit mask ----
    const float4* rp = (const float4*)(img + (lane << 6) + (h << 4));
    unsigned int m = 0;
    #pragma unroll
    for (int q = 0; q < 4; ++q) {
        float4 v = rp[q];
        m |= (unsigned)(v.x > thr) << (4 * q + 0);
        m |= (unsigned)(v.y > thr) << (4 * q + 1);
        m |= (unsigned)(v.z > thr) << (4 * q + 2);
        m |= (unsigned)(v.w > thr) << (4 * q + 3);
    }

    // ---- init my 8 UF slots (only my wave touches them pre-barrier) ----
    #pragma unroll
    for (int k = 0; k < 8; ++k) {
        int s = ((h * 8 + k) << 6) | lane;
        P[s] = s;
    }

    const unsigned um = m & 0xFFFFu;
    unsigned up        = (unsigned)__shfl_up((int)um, 1, 64);
    unsigned starts    = um & ~(um << 1) & 0xFFFFu;       // run starts
    unsigned starts_up = (unsigned)__shfl_up((int)starts, 1, 64);
    if (lane == 0) { up = 0u; starts_up = 0u; }

    const int px    = __popc(um);
    int       eh    = __popc(um & (um >> 1));             // horiz edges in quarter
    const int ev    = __popc(um & up);                    // vert edges in quarter
    const int nruns = __popc(starts);

    // ---- boundary descriptors (written pre-barrier, read post-barrier) ----
    if (h < 3)   // run containing col15 is the last-starting run: index nruns-1
        bL[h][lane] = ((um >> 15) & 1u) ? (((h * 8 + (nruns - 1)) << 6) | lane) : -1;
    if (h > 0)   // if col 16h is set, it is a run start: index 0
        bR[h - 1][lane] = (um & 1u) ? (((h * 8) << 6) | lane) : -1;

    // ---- within-quarter vertical-overlap unions (own slots only: no barrier) ----
    int merges = 0;
    unsigned ov = um & up;
    unsigned ss = ov & ~(ov << 1) & 0xFFFFu;              // segment starts
    while (ss) {
        int j = __ffs(ss) - 1;
        ss &= ss - 1;
        unsigned le = (2u << j) - 1;                      // bits [0..j]
        int kc = __popc(starts    & le) - 1;
        int ku = __popc(starts_up & le) - 1;
        merges += unite(P, ((h * 8 + kc) << 6) | lane, ((h * 8 + ku) << 6) | (lane - 1));
    }

    __syncthreads();   // all inits + bL/bR + (disjoint) within-unions visible

    // ---- boundary unions + crossing horizontal edges (waves 0..2) ----
    if (h < 3) {
        int l = bL[h][lane], r = bR[h][lane];
        if (l >= 0 && r >= 0) { eh++; merges += unite(P, l, r); }
    }

    // ---- packed {px(13)|eh(12)|ev(12)|nruns(12)|merges(12)} wave reduce ----
    // block totals: px<=4096, eh<=4032, ev<=4032, nruns<=2048, merges<2048
    ull pk = (ull)px
           | ((ull)eh     << 13)
           | ((ull)ev     << 25)
           | ((ull)nruns  << 37)
           | ((ull)merges << 49);
    #pragma unroll
    for (int o = 32; o > 0; o >>= 1)
        pk += __shfl_down(pk, o, 64);

    if (lane == 0) ws[(size_t)bid * 4 + h] = pk;          // plain store
}

// 8 blocks: block b combines 200 (c,t) tiles' 4 wave-partials each,
// does the betti math + gt |diff|, plain-stores out[b].
__global__ __launch_bounds__(256)
void betti_final(const ull* __restrict__ ws,
                 const int* __restrict__ gt,              // [8,3,100,2]
                 float* __restrict__ out)                 // [8]
{
    __shared__ int wsum[4];
    const int b = blockIdx.x;
    const int tid = threadIdx.x;

    int contrib = 0;
    if (tid < 200) {                                      // tid = c*100 + t
        const ull* p = ws + (size_t)(b * 200 + tid) * 4;
        ull s = p[0] + p[1] + p[2] + p[3];
        const int px = (int)( s        & 0x1FFF);
        const int eh = (int)((s >> 13) & 0xFFF);
        const int ev = (int)((s >> 25) & 0xFFF);
        const int nr = (int)((s >> 37) & 0xFFF);
        const int mg = (int)((s >> 49) & 0xFFF);
        const int b0 = nr - mg;
        const int b1 = b0 - (px - (eh + ev));

        const int c = tid / 100;
        const int t = tid - c * 100;
        int d;
        if (c == 0) {
            const int* g0 = gt + (((size_t)b * 3 + 0) * NT + t) * 2;
            const int* g2 = gt + (((size_t)b * 3 + 2) * NT + t) * 2;
            d = b0 - g0[0]; contrib += d < 0 ? -d : d;
            d = b1 - g0[1]; contrib += d < 0 ? -d : d;
            d = b0 - g2[0]; contrib += d < 0 ? -d : d;
            d = b1 - g2[1]; contrib += d < 0 ? -d : d;
        } else {
            const int* g1 = gt + (((size_t)b * 3 + 1) * NT + t) * 2;
            d = b0 - g1[0]; contrib += d < 0 ? -d : d;
            d = b1 - g1[1]; contrib += d < 0 ? -d : d;
        }
    }

    #pragma unroll
    for (int o = 32; o > 0; o >>= 1) contrib += __shfl_down(contrib, o, 64);
    if ((tid & 63) == 0) wsum[tid >> 6] = contrib;
    __syncthreads();
    if (tid == 0)
        out[b] = (float)(wsum[0] + wsum[1] + wsum[2] + wsum[3]);
}

extern "C" void kernel_launch(void* const* d_in, const int* in_sizes, int n_in,
                              void* d_out, int out_size, void* d_ws, size_t ws_size,
                              hipStream_t stream) {
    const float* prob = (const float*)d_in[0];   // [8,3,64,64] f32
    const int*   gt   = (const int*)d_in[1];     // [8,3,100,2] i32
    float* out = (float*)d_out;                  // [8] f32
    ull* ws = (ull*)d_ws;                        // 1600*4 u64 scratch

    const int nblocks = 8 * 2 * NT;   // 1600 blocks, one per (b,c,t)
    betti_partial<<<nblocks, 256, 0, stream>>>(prob, ws);
    betti_final<<<8, 256, 0, stream>>>(ws, gt, out);
}